// Round 14
// baseline (414.243 us; speedup 1.0000x reference)
//
#include <hip/hip_runtime.h>
#include <math.h>

#define N_TOK 32768
#define DIM   512
#define NEXP  64
#define HID   1024
#define CAP   512

typedef float  f32x4  __attribute__((ext_vector_type(4)));
typedef short  bf16x8 __attribute__((ext_vector_type(8)));
typedef unsigned short u16;

#define GET4(v, jj) ((jj) == 0 ? (v).x : (jj) == 1 ? (v).y : (jj) == 2 ? (v).z : (v).w)

__device__ __forceinline__ u16 f2bf(float f) {
  unsigned u = __float_as_uint(f);
  u += 0x7FFFu + ((u >> 16) & 1u);   // RNE
  return (u16)(u >> 16);
}
__device__ __forceinline__ unsigned enc_f(float f) {  // monotone f32 -> u32
  unsigned u = __float_as_uint(f);
  return (u & 0x80000000u) ? ~u : (u | 0x80000000u);
}
__device__ __forceinline__ float dec_f(unsigned k) {
  unsigned u = (k & 0x80000000u) ? (k & 0x7FFFFFFFu) : ~k;
  return __uint_as_float(u);
}
__device__ __forceinline__ void gl16(const u16* g, u16* l) {
  __builtin_amdgcn_global_load_lds(
      (const __attribute__((address_space(1))) unsigned int*)g,
      (__attribute__((address_space(3))) unsigned int*)l, 16, 0, 0);
}
// exact-enough erf (A&S 7.1.26, |eps|<=1.5e-7) -> gelu
__device__ __forceinline__ float gelu_f(float v) {
  float x = fabsf(v) * 0.70710678118654752f;
  float tt = 1.0f / (1.0f + 0.3275911f * x);
  float poly = tt * (0.254829592f + tt * (-0.284496736f + tt * (1.421413741f +
               tt * (-1.453152027f + tt * 1.061405429f))));
  float erfabs = 1.0f - poly * __expf(-x * x);
  float erfv = v >= 0.f ? erfabs : -erfabs;
  return 0.5f * v * (1.0f + erfv);
}

// ---------------- router: LDS-tiled fp32 SGEMM, 64 tok x 64 exp per block ----------------
// Also emits xb = bf16(x) as a by-product.
__global__ __launch_bounds__(256)
void router_kernel(const float* __restrict__ x, const float* __restrict__ rw,
                   float* __restrict__ logitsT, u16* __restrict__ xb) {
  __shared__ float As[32][68];   // [k][m]
  __shared__ float Bs[32][68];   // [k][e]
  const int t = threadIdx.x;
  const int n0 = blockIdx.x * 64;
  const int ty = t >> 4, tx = t & 15;
  const int am = t >> 2, akq = (t & 3) * 8;
  const int bk = t >> 3, beq = (t & 7) * 8;
  const float* xrow = x + (size_t)(n0 + am) * DIM + akq;
  u16* xbrow = xb ? (xb + (size_t)(n0 + am) * DIM + akq) : (u16*)0;
  const float* brow = rw + (size_t)bk * NEXP + beq;

  float acc[4][4] = {};
  for (int k0 = 0; k0 < DIM; k0 += 32) {
    float4 a0 = *(const float4*)(xrow + k0);
    float4 a1 = *(const float4*)(xrow + k0 + 4);
    float4 b0 = *(const float4*)(brow + (size_t)k0 * NEXP);
    float4 b1 = *(const float4*)(brow + (size_t)k0 * NEXP + 4);
    if (xbrow) {
      uint4 o;
      o.x = f2bf(a0.x) | ((unsigned)f2bf(a0.y) << 16);
      o.y = f2bf(a0.z) | ((unsigned)f2bf(a0.w) << 16);
      o.z = f2bf(a1.x) | ((unsigned)f2bf(a1.y) << 16);
      o.w = f2bf(a1.z) | ((unsigned)f2bf(a1.w) << 16);
      *(uint4*)(xbrow + k0) = o;
    }
    __syncthreads();
    As[akq + 0][am] = a0.x; As[akq + 1][am] = a0.y;
    As[akq + 2][am] = a0.z; As[akq + 3][am] = a0.w;
    As[akq + 4][am] = a1.x; As[akq + 5][am] = a1.y;
    As[akq + 6][am] = a1.z; As[akq + 7][am] = a1.w;
    *(float4*)&Bs[bk][beq] = b0;
    *(float4*)&Bs[bk][beq + 4] = b1;
    __syncthreads();
#pragma unroll
    for (int k = 0; k < 32; ++k) {
      float4 av = *(const float4*)&As[k][ty * 4];
      float4 bv = *(const float4*)&Bs[k][tx * 4];
#pragma unroll
      for (int i = 0; i < 4; ++i)
#pragma unroll
        for (int j = 0; j < 4; ++j)
          acc[i][j] += GET4(av, i) * GET4(bv, j);
    }
  }
#pragma unroll
  for (int j = 0; j < 4; ++j) {
    float4 o; o.x = acc[0][j]; o.y = acc[1][j]; o.z = acc[2][j]; o.w = acc[3][j];
    *(float4*)(logitsT + (size_t)(tx * 4 + j) * N_TOK + n0 + ty * 4) = o;
  }
}

// ------------- topk: per-wave histograms (16x contention reduction) -------------
__global__ __launch_bounds__(1024)
void topk_kernel(const float* __restrict__ logitsT, int* __restrict__ tok_idx,
                 float* __restrict__ expw, float* __restrict__ auxout) {
  const int e = blockIdx.x;
  const int t = threadIdx.x;
  const int w = t >> 6;                 // wave 0..15
  const float* row = logitsT + (size_t)e * N_TOK;

  unsigned key[32];          // token n = j*1024 + t
#pragma unroll
  for (int j = 0; j < 32; ++j) key[j] = enc_f(row[j * 1024 + t]);

  __shared__ unsigned ured[1024];
  __shared__ float    fred[1024];
  __shared__ unsigned h16[16][256];     // per-wave histograms, 16 KB
  __shared__ unsigned hist[256];
  __shared__ unsigned sh_chosen, sh_rem, sh_x, sh_pos;

#define HIST_CLEAR() do { \
    ((unsigned*)h16)[t] = 0; ((unsigned*)h16)[t + 1024] = 0; \
    ((unsigned*)h16)[t + 2048] = 0; ((unsigned*)h16)[t + 3072] = 0; \
    __syncthreads(); } while (0)
#define HIST_FOLD() do { \
    __syncthreads(); \
    if (t < 256) { unsigned s_ = 0; \
      _Pragma("unroll") for (int q_ = 0; q_ < 16; ++q_) s_ += h16[q_][t]; \
      hist[t] = s_; } \
    __syncthreads(); } while (0)

  unsigned km = 0;
#pragma unroll
  for (int j = 0; j < 32; ++j) km = key[j] > km ? key[j] : km;
  ured[t] = km;
  __syncthreads();
  for (int s = 512; s > 0; s >>= 1) {
    if (t < s) { unsigned o = ured[t + s]; if (o > ured[t]) ured[t] = o; }
    __syncthreads();
  }
  const float m = dec_f(ured[0]);

  float ssum = 0.f;
#pragma unroll
  for (int j = 0; j < 32; ++j) ssum += expf(dec_f(key[j]) - m);
  fred[t] = ssum;
  __syncthreads();
  for (int s = 512; s > 0; s >>= 1) {
    if (t < s) fred[t] += fred[t + s];
    __syncthreads();
  }
  const float invZ = 1.0f / fred[0];

  if (t == 0) sh_rem = CAP;
  unsigned live = 0xFFFFFFFFu;
  unsigned prefix = 0;
  for (int pass = 0; pass < 4; ++pass) {
    const int shift = 24 - pass * 8;
    HIST_CLEAR();
#pragma unroll
    for (int j = 0; j < 32; ++j)
      if (live & (1u << j)) atomicAdd(&h16[w][(key[j] >> shift) & 0xFFu], 1u);
    HIST_FOLD();
    if (t == 0) {
      unsigned need = sh_rem, accum = 0;
      int found = 0;
      for (int b = 255; b >= 0; --b) {
        unsigned cn = hist[b];
        if (!found) {
          if (accum + cn >= need) { sh_chosen = (unsigned)b; sh_rem = need - accum; found = 1; }
          else accum += cn;
        }
      }
    }
    __syncthreads();
    const unsigned ch = sh_chosen;
#pragma unroll
    for (int j = 0; j < 32; ++j)
      if (((key[j] >> shift) & 0xFFu) != ch) live &= ~(1u << j);
    prefix = (prefix << 8) | ch;
    __syncthreads();
  }
  const unsigned ustar = prefix;

  if (t == 0) sh_pos = 0;
  __syncthreads();
#pragma unroll
  for (int j = 0; j < 32; ++j) {
    if (key[j] > ustar) {
      unsigned p = atomicAdd(&sh_pos, 1u);
      tok_idx[e * CAP + p] = j * 1024 + t;
      expw[e * CAP + p] = expf(dec_f(key[j]) - m) * invZ;
    }
  }
  __syncthreads();
  const unsigned padv = CAP - sh_pos;

  // tie-break: padv smallest token indices among keys == ustar
  HIST_CLEAR();
#pragma unroll
  for (int j = 0; j < 32; ++j)
    if (live & (1u << j)) atomicAdd(&h16[w][(j * 1024 + t) >> 7], 1u);
  HIST_FOLD();
  if (t == 0) {
    unsigned accum = 0;
    int found = 0;
    for (int b = 0; b < 256; ++b) {
      unsigned cn = hist[b];
      if (!found) {
        if (accum + cn >= padv) { sh_chosen = (unsigned)b; sh_rem = padv - accum; found = 1; }
        else accum += cn;
      }
    }
  }
  __syncthreads();
  const unsigned hb = sh_chosen, rem = sh_rem;
  HIST_CLEAR();
#pragma unroll
  for (int j = 0; j < 32; ++j)
    if (live & (1u << j)) {
      int n = j * 1024 + t;
      if ((unsigned)(n >> 7) == hb) atomicAdd(&h16[w][n & 127], 1u);
    }
  HIST_FOLD();
  if (t == 0) {
    unsigned accum = 0;
    int found = 0;
    for (int b = 0; b < 128; ++b) {
      unsigned cn = hist[b];
      if (!found) {
        if (accum + cn >= rem) { sh_x = (hb << 7) | (unsigned)b; found = 1; }
        else accum += cn;
      }
    }
  }
  __syncthreads();
  const int X = (int)sh_x;
#pragma unroll
  for (int j = 0; j < 32; ++j)
    if (live & (1u << j)) {
      int n = j * 1024 + t;
      if (n <= X) {
        unsigned p = atomicAdd(&sh_pos, 1u);
        tok_idx[e * CAP + p] = n;
        expw[e * CAP + p] = expf(dec_f(key[j]) - m) * invZ;
      }
    }
  if (e == 0 && t == 0) { auxout[0] = 2.44140625e-4f; auxout[1] = 0.015625f; }
#undef HIST_CLEAR
#undef HIST_FOLD
}

// ---------------- prep: per-expert transpose+cvt: f32 [E][R][C] -> bf16 [E][C][R] ----------------
__global__ __launch_bounds__(256)
void transpose_cvt_kernel(const float* __restrict__ in, u16* __restrict__ outp,
                          int R, int C) {
  __shared__ u16 tile[64][66];
  const int e = blockIdx.z;
  const int r0 = blockIdx.y * 64, c0 = blockIdx.x * 64;
  const int t = threadIdx.x;
  {
    const int r = t >> 2, cs = (t & 3) * 16;
    const float* ip = in + ((size_t)e * R + (r0 + r)) * C + c0 + cs;
#pragma unroll
    for (int q = 0; q < 4; ++q) {
      float4 v = *(const float4*)(ip + q * 4);
      tile[r][cs + q * 4 + 0] = f2bf(v.x);
      tile[r][cs + q * 4 + 1] = f2bf(v.y);
      tile[r][cs + q * 4 + 2] = f2bf(v.z);
      tile[r][cs + q * 4 + 3] = f2bf(v.w);
    }
  }
  __syncthreads();
  {
    const int c = t >> 2, rs = (t & 3) * 16;
    u16* op = outp + ((size_t)e * C + (c0 + c)) * R + r0 + rs;
    uint4 o0, o1;
    o0.x = tile[rs + 0][c]  | ((unsigned)tile[rs + 1][c]  << 16);
    o0.y = tile[rs + 2][c]  | ((unsigned)tile[rs + 3][c]  << 16);
    o0.z = tile[rs + 4][c]  | ((unsigned)tile[rs + 5][c]  << 16);
    o0.w = tile[rs + 6][c]  | ((unsigned)tile[rs + 7][c]  << 16);
    o1.x = tile[rs + 8][c]  | ((unsigned)tile[rs + 9][c]  << 16);
    o1.y = tile[rs + 10][c] | ((unsigned)tile[rs + 11][c] << 16);
    o1.z = tile[rs + 12][c] | ((unsigned)tile[rs + 13][c] << 16);
    o1.w = tile[rs + 14][c] | ((unsigned)tile[rs + 15][c] << 16);
    *(uint4*)(op) = o0;
    *(uint4*)(op + 8) = o1;
  }
}

// ===================== bf16 GEMMs: BM128 x BN256, BK=32, 3-buf depth-2, 72KB LDS (2 blocks/CU) =====================
#define A_EL 4096      // 128*32 elems (8 KB)
#define B_EL 8192      // 256*32 elems (16 KB)

#define LDSW(base, row, hi4v) \
  (*(const bf16x8*)((const char*)(base) + (row) * 64 + ((((hi4v) ^ (((row) >> 1) & 3))) << 4)))

#define STG3(bs, k0) do { \
  gl16(aSrc + (k0), AsmF + (bs) * A_EL + wOff); \
  gl16(bSrc0 + (k0), BsmF + (bs) * B_EL + wOff); \
  gl16(bSrc1 + (k0), BsmF + (bs) * B_EL + wOff + 4096); \
} while (0)

__global__ __launch_bounds__(512, 4)
void fc1_bf(const u16* __restrict__ xb, const int* __restrict__ tok_idx,
            const u16* __restrict__ w1t, const float* __restrict__ b1,
            u16* __restrict__ h) {
  const int p = blockIdx.x;
  const int l = (p & 7) * 128 + (p >> 3);        // bijective XCD remap (1024 = 8*128)
  const int e  = l >> 4;
  const int mt = (l >> 2) & 3;
  const int nt = l & 3;
  const int m0 = mt * 128, n0 = nt * 256;
  const int t = threadIdx.x;
  const int lane = t & 63, wave = t >> 6;        // 8 waves
  const int wm = wave >> 2, wn = wave & 3;       // 2m x 4n, per-wave C 64x64

  __shared__ __align__(16) u16 AsmF[3 * A_EL];   // 24 KB
  __shared__ __align__(16) u16 BsmF[3 * B_EL];   // 48 KB

  const int kc = ((lane & 3) ^ ((lane >> 3) & 3)) * 8;  // pre-swizzled k elem offset
  const int rloc = lane >> 2;                    // 0..15
  const int wOff = wave * 512;                   // 16 rows x 32 elems

  const int arow = wave * 16 + rloc;             // 0..127
  const int tok = tok_idx[e * CAP + m0 + arow];
  const u16* aSrc  = xb + (size_t)tok * DIM + kc;
  const u16* bSrc0 = w1t + ((size_t)e * HID + n0 + arow) * DIM + kc;
  const u16* bSrc1 = w1t + ((size_t)e * HID + n0 + 128 + arow) * DIM + kc;

  f32x4 acc[4][4] = {};
  const int lr = lane & 15, hi4 = lane >> 4;

  STG3(0, 0);     // K-tile 0 -> buf 0
  STG3(1, 32);    // K-tile 1 -> buf 1
  int cur = 0;
  const int KT = DIM / 32;                       // 16
  for (int tt = 0; tt < KT; ++tt) {
    if (tt < KT - 1) asm volatile("s_waitcnt vmcnt(3)" ::: "memory");
    else             asm volatile("s_waitcnt vmcnt(0)" ::: "memory");
    __builtin_amdgcn_s_barrier();
    const u16* Ab = AsmF + cur * A_EL;
    const u16* Bb = BsmF + cur * B_EL;
    bf16x8 af[4], bf[4];
#pragma unroll
    for (int mi = 0; mi < 4; ++mi) af[mi] = LDSW(Ab, wm * 64 + mi * 16 + lr, hi4);
#pragma unroll
    for (int ni = 0; ni < 4; ++ni) bf[ni] = LDSW(Bb, wn * 64 + ni * 16 + lr, hi4);
    if (tt + 2 < KT) {
      const int bs = (tt + 2) % 3;
      STG3(bs, (tt + 2) * 32);
    }
    __builtin_amdgcn_s_setprio(1);
#pragma unroll
    for (int mi = 0; mi < 4; ++mi)
#pragma unroll
      for (int ni = 0; ni < 4; ++ni)
        acc[mi][ni] = __builtin_amdgcn_mfma_f32_16x16x32_bf16(af[mi], bf[ni], acc[mi][ni], 0, 0, 0);
    __builtin_amdgcn_s_setprio(0);
    __builtin_amdgcn_s_barrier();
    cur = cur == 2 ? 0 : cur + 1;
  }

  const int lq = lane >> 4, lc = lane & 15;
#pragma unroll
  for (int nj = 0; nj < 4; ++nj) {
    const int n_l = wn * 64 + nj * 16 + lc;
    const float bias = b1[e * HID + n0 + n_l];
#pragma unroll
    for (int mi = 0; mi < 4; ++mi) {
#pragma unroll
      for (int j = 0; j < 4; ++j) {
        const int m_l = wm * 64 + mi * 16 + lq * 4 + j;
        float v = acc[mi][nj][j] + bias;
        h[((size_t)(e * CAP + m0 + m_l)) * HID + (n0 + n_l)] = f2bf(gelu_f(v));
      }
    }
  }
}

__global__ __launch_bounds__(512, 4)
void fc2_bf(const u16* __restrict__ h, const u16* __restrict__ w2t,
            const float* __restrict__ b2, const int* __restrict__ tok_idx,
            const float* __restrict__ expw, float* __restrict__ out) {
  const int p = blockIdx.x;
  const int l = (p & 7) * 64 + (p >> 3);         // bijective XCD remap (512 = 8*64)
  const int e  = l >> 3;
  const int mt = (l >> 1) & 3;
  const int nt = l & 1;
  const int m0 = mt * 128, n0 = nt * 256;
  const int t = threadIdx.x;
  const int lane = t & 63, wave = t >> 6;
  const int wm = wave >> 2, wn = wave & 3;

  __shared__ __align__(16) u16 AsmF[3 * A_EL];
  __shared__ __align__(16) u16 BsmF[3 * B_EL];

  const int kc = ((lane & 3) ^ ((lane >> 3) & 3)) * 8;
  const int rloc = lane >> 2;
  const int wOff = wave * 512;

  const int arow = wave * 16 + rloc;
  const u16* aSrc  = h + ((size_t)(e * CAP + m0 + arow)) * HID + kc;
  const u16* bSrc0 = w2t + ((size_t)e * DIM + n0 + arow) * HID + kc;
  const u16* bSrc1 = w2t + ((size_t)e * DIM + n0 + 128 + arow) * HID + kc;

  f32x4 acc[4][4] = {};
  const int lr = lane & 15, hi4 = lane >> 4;

  STG3(0, 0);
  STG3(1, 32);
  int cur = 0;
  const int KT = HID / 32;                       // 32
  for (int tt = 0; tt < KT; ++tt) {
    if (tt < KT - 1) asm volatile("s_waitcnt vmcnt(3)" ::: "memory");
    else             asm volatile("s_waitcnt vmcnt(0)" ::: "memory");
    __builtin_amdgcn_s_barrier();
    const u16* Ab = AsmF + cur * A_EL;
    const u16* Bb = BsmF + cur * B_EL;
    bf16x8 af[4], bf[4];
#pragma unroll
    for (int mi = 0; mi < 4; ++mi) af[mi] = LDSW(Ab, wm * 64 + mi * 16 + lr, hi4);
#pragma unroll
    for (int ni = 0; ni < 4; ++ni) bf[ni] = LDSW(Bb, wn * 64 + ni * 16 + lr, hi4);
    if (tt + 2 < KT) {
      const int bs = (tt + 2) % 3;
      STG3(bs, (tt + 2) * 32);
    }
    __builtin_amdgcn_s_setprio(1);
#pragma unroll
    for (int mi = 0; mi < 4; ++mi)
#pragma unroll
      for (int ni = 0; ni < 4; ++ni)
        acc[mi][ni] = __builtin_amdgcn_mfma_f32_16x16x32_bf16(af[mi], bf[ni], acc[mi][ni], 0, 0, 0);
    __builtin_amdgcn_s_setprio(0);
    __builtin_amdgcn_s_barrier();
    cur = cur == 2 ? 0 : cur + 1;
  }

  const int lq = lane >> 4, lc = lane & 15;
  int   tokm[4][4];
  float wgt[4][4];
#pragma unroll
  for (int mi = 0; mi < 4; ++mi)
#pragma unroll
    for (int j = 0; j < 4; ++j) {
      const int m_l = wm * 64 + mi * 16 + lq * 4 + j;
      tokm[mi][j] = tok_idx[e * CAP + m0 + m_l];
      wgt[mi][j]  = expw[e * CAP + m0 + m_l];
    }
#pragma unroll
  for (int nj = 0; nj < 4; ++nj) {
    const int n_l = wn * 64 + nj * 16 + lc;
    const float bias = b2[e * DIM + n0 + n_l];
#pragma unroll
    for (int mi = 0; mi < 4; ++mi)
#pragma unroll
      for (int j = 0; j < 4; ++j) {
        float v = (acc[mi][nj][j] + bias) * wgt[mi][j];
        atomicAdd(out + (size_t)tokm[mi][j] * DIM + (n0 + n_l), v);
      }
  }
}

// ===================== fallback f32-input GEMMs (ws too small) =====================
#define SWZ(row, cb) ((cb) ^ (((((row) >> 3) ^ (row)) & 7) << 4))

__global__ __launch_bounds__(256)
void fc1_kernel(const float* __restrict__ x, const int* __restrict__ tok_idx,
                const float* __restrict__ w1, const float* __restrict__ b1,
                u16* __restrict__ h) {
  const int bx = blockIdx.x;
  const int e  = bx >> 5;
  const int mt = (bx >> 3) & 3;
  const int nt = bx & 7;
  const int m0 = mt * 128, n0 = nt * 128;
  const int t = threadIdx.x;
  const int lane = t & 63, wave = t >> 6;
  const int wm = wave >> 1, wn = wave & 1;

  __shared__ __align__(16) u16 Asm[128 * 64];
  __shared__ __align__(16) u16 Bsm[128 * 64];

  const int arq = t & 31, akq = t >> 5;
  int tokr[4];
#pragma unroll
  for (int j = 0; j < 4; ++j) tokr[j] = tok_idx[e * CAP + m0 + arq * 4 + j];
  const int nq = t & 31, kq = t >> 5;
  const float* bptr = w1 + (size_t)e * DIM * HID + n0 + nq * 4;

  f32x4 acc[4][4] = {};

  for (int k0 = 0; k0 < DIM; k0 += 64) {
    float4 av0[4], av1[4];
#pragma unroll
    for (int j = 0; j < 4; ++j) {
      const float* ap = x + (size_t)tokr[j] * DIM + k0 + akq * 8;
      av0[j] = *(const float4*)(ap);
      av1[j] = *(const float4*)(ap + 4);
    }
    float4 bv[8];
#pragma unroll
    for (int kk = 0; kk < 8; ++kk)
      bv[kk] = *(const float4*)(bptr + (size_t)(k0 + kq * 8 + kk) * HID);
    __syncthreads();
#pragma unroll
    for (int j = 0; j < 4; ++j) {
      const int row = arq * 4 + j;
      ushort4 w0, w1v;
      w0.x = f2bf(av0[j].x); w0.y = f2bf(av0[j].y); w0.z = f2bf(av0[j].z); w0.w = f2bf(av0[j].w);
      w1v.x = f2bf(av1[j].x); w1v.y = f2bf(av1[j].y); w1v.z = f2bf(av1[j].z); w1v.w = f2bf(av1[j].w);
      *(ushort4*)((char*)Asm + row * 128 + SWZ(row, (akq * 8 + 0) * 2)) = w0;
      *(ushort4*)((char*)Asm + row * 128 + SWZ(row, (akq * 8 + 4) * 2)) = w1v;
    }
#pragma unroll
    for (int g = 0; g < 2; ++g) {
#pragma unroll
      for (int j = 0; j < 4; ++j) {
        ushort4 wv;
        wv.x = f2bf(GET4(bv[g * 4 + 0], j));
        wv.y = f2bf(GET4(bv[g * 4 + 1], j));
        wv.z = f2bf(GET4(bv[g * 4 + 2], j));
        wv.w = f2bf(GET4(bv[g * 4 + 3], j));
        const int row = nq * 4 + j;
        const int cb = (kq * 8 + g * 4) * 2;
        *(ushort4*)((char*)Bsm + row * 128 + SWZ(row, cb)) = wv;
      }
    }
    __syncthreads();
#pragma unroll
    for (int ks = 0; ks < 2; ++ks) {
      bf16x8 af[4], bf[4];
#pragma unroll
      for (int mi = 0; mi < 4; ++mi) {
        const int row = wm * 64 + mi * 16 + (lane & 15);
        const int cb = ks * 64 + (lane >> 4) * 16;
        af[mi] = *(const bf16x8*)((const char*)Asm + row * 128 + SWZ(row, cb));
      }
#pragma unroll
      for (int ni = 0; ni < 4; ++ni) {
        const int row = wn * 64 + ni * 16 + (lane & 15);
        const int cb = ks * 64 + (lane >> 4) * 16;
        bf[ni] = *(const bf16x8*)((const char*)Bsm + row * 128 + SWZ(row, cb));
      }
#pragma unroll
      for (int mi = 0; mi < 4; ++mi)
#pragma unroll
        for (int ni = 0; ni < 4; ++ni)
          acc[mi][ni] = __builtin_amdgcn_mfma_f32_16x16x32_bf16(af[mi], bf[ni], acc[mi][ni], 0, 0, 0);
    }
  }
  const int lq = lane >> 4, lc = lane & 15;
#pragma unroll
  for (int ni = 0; ni < 4; ++ni) {
    const int n_l = wn * 64 + ni * 16 + lc;
    const float bias = b1[e * HID + n0 + n_l];
#pragma unroll
    for (int mi = 0; mi < 4; ++mi) {
#pragma unroll
      for (int j = 0; j < 4; ++j) {
        const int m_l = wm * 64 + mi * 16 + lq * 4 + j;
        float v = acc[mi][ni][j] + bias;
        h[((size_t)(e * CAP + m0 + m_l)) * HID + (n0 + n_l)] = f2bf(gelu_f(v));
      }
    }
  }
}

__global__ __launch_bounds__(256)
void fc2_kernel(const u16* __restrict__ h, const float* __restrict__ w2,
                const float* __restrict__ b2, const int* __restrict__ tok_idx,
                const float* __restrict__ expw, float* __restrict__ out) {
  const int bx = blockIdx.x;
  const int e  = bx >> 4;
  const int mt = (bx >> 2) & 3;
  const int nt = bx & 3;
  const int m0 = mt * 128, n0 = nt * 128;
  const int t = threadIdx.x;
  const int lane = t & 63, wave = t >> 6;
  const int wm = wave >> 1, wn = wave & 1;

  __shared__ __align__(16) u16 Asm[128 * 64];
  __shared__ __align__(16) u16 Bsm[128 * 64];

  const int arq = t & 31, akq = t >> 5;
  const u16* aptr0 = h + ((size_t)(e * CAP + m0 + arq * 4)) * HID + akq * 8;
  const int nq = t & 31, kq = t >> 5;
  const float* bptr = w2 + (size_t)e * HID * DIM + n0 + nq * 4;

  f32x4 acc[4][4] = {};

  for (int k0 = 0; k0 < HID; k0 += 64) {
    uint4 av[4];
#pragma unroll
    for (int j = 0; j < 4; ++j)
      av[j] = *(const uint4*)(aptr0 + (size_t)j * HID + k0);
    float4 bv[8];
#pragma unroll
    for (int kk = 0; kk < 8; ++kk)
      bv[kk] = *(const float4*)(bptr + (size_t)(k0 + kq * 8 + kk) * DIM);
    __syncthreads();
#pragma unroll
    for (int j = 0; j < 4; ++j) {
      const int row = arq * 4 + j;
      *(uint4*)((char*)Asm + row * 128 + SWZ(row, akq * 16)) = av[j];
    }
#pragma unroll
    for (int g = 0; g < 2; ++g) {
#pragma unroll
      for (int j = 0; j < 4; ++j) {
        ushort4 wv;
        wv.x = f2bf(GET4(bv[g * 4 + 0], j));
        wv.y = f2bf(GET4(bv[g * 4 + 1], j));
        wv.z = f2bf(GET4(bv[g * 4 + 2], j));
        wv.w = f2bf(GET4(bv[g * 4 + 3], j));
        const int row = nq * 4 + j;
        const int cb = (kq * 8 + g * 4) * 2;
        *(ushort4*)((char*)Bsm + row * 128 + SWZ(row, cb)) = wv;
      }
    }
    __syncthreads();
#pragma unroll
    for (int ks = 0; ks < 2; ++ks) {
      bf16x8 af[4], bf[4];
#pragma unroll
      for (int mi = 0; mi < 4; ++mi) {
        const int row = wm * 64 + mi * 16 + (lane & 15);
        const int cb = ks * 64 + (lane >> 4) * 16;
        af[mi] = *(const bf16x8*)((const char*)Asm + row * 128 + SWZ(row, cb));
      }
#pragma unroll
      for (int ni = 0; ni < 4; ++ni) {
        const int row = wn * 64 + ni * 16 + (lane & 15);
        const int cb = ks * 64 + (lane >> 4) * 16;
        bf[ni] = *(const bf16x8*)((const char*)Bsm + row * 128 + SWZ(row, cb));
      }
#pragma unroll
      for (int mi = 0; mi < 4; ++mi)
#pragma unroll
        for (int ni = 0; ni < 4; ++ni)
          acc[mi][ni] = __builtin_amdgcn_mfma_f32_16x16x32_bf16(af[mi], bf[ni], acc[mi][ni], 0, 0, 0);
    }
  }
  const int lq = lane >> 4, lc = lane & 15;
  int   tokm[4][4];
  float wgt[4][4];
#pragma unroll
  for (int mi = 0; mi < 4; ++mi)
#pragma unroll
    for (int j = 0; j < 4; ++j) {
      const int m_l = wm * 64 + mi * 16 + lq * 4 + j;
      tokm[mi][j] = tok_idx[e * CAP + m0 + m_l];
      wgt[mi][j]  = expw[e * CAP + m0 + m_l];
    }
#pragma unroll
  for (int ni = 0; ni < 4; ++ni) {
    const int n_l = wn * 64 + ni * 16 + lc;
    const float bias = b2[e * DIM + n0 + n_l];
#pragma unroll
    for (int mi = 0; mi < 4; ++mi)
#pragma unroll
      for (int j = 0; j < 4; ++j) {
        float v = (acc[mi][ni][j] + bias) * wgt[mi][j];
        atomicAdd(out + (size_t)tokm[mi][j] * DIM + (n0 + n_l), v);
      }
  }
}

extern "C" void kernel_launch(void* const* d_in, const int* in_sizes, int n_in,
                              void* d_out, int out_size, void* d_ws, size_t ws_size,
                              hipStream_t stream) {
  const float* x  = (const float*)d_in[0];
  const float* rw = (const float*)d_in[1];
  const float* w1 = (const float*)d_in[2];
  const float* b1 = (const float*)d_in[3];
  const float* w2 = (const float*)d_in[4];
  const float* b2 = (const float*)d_in[5];
  float* out = (float*)d_out;

  char* ws = (char*)d_ws;
  const size_t MB = 1u << 20;
  float* logits = (float*)ws;                                   // [0, 8M)
  int*   toki   = (int*)(ws + 8 * MB);                          // 128 KB
  float* ew     = (float*)(ws + 8 * MB + (128u << 10));         // 128 KB

  const size_t off_xb = 8 * MB + (256u << 10);   // 8.25M
  const size_t off_wt = off_xb + 32 * MB;        // 40.25M
  const size_t off_h  = off_wt + 64 * MB;        // 104.25M
  const size_t need   = off_h + 64 * MB;         // 168.25M
  const bool big = (ws_size >= need);

  u16* xb = big ? (u16*)(ws + off_xb) : (u16*)0;

  (void)hipMemsetAsync(d_out, 0, (size_t)out_size * sizeof(float), stream);
  router_kernel<<<dim3(512), dim3(256), 0, stream>>>(x, rw, logits, xb);
  topk_kernel<<<dim3(64), dim3(1024), 0, stream>>>(logits, toki, ew, out + (size_t)N_TOK * DIM);

  if (big) {
    u16* wt  = (u16*)(ws + off_wt);
    u16* h   = (u16*)(ws + off_h);
    transpose_cvt_kernel<<<dim3(16, 8, 64), dim3(256), 0, stream>>>(w1, wt, 512, 1024);
    fc1_bf<<<dim3(1024), dim3(512), 0, stream>>>(xb, toki, wt, b1, h);
    transpose_cvt_kernel<<<dim3(8, 16, 64), dim3(256), 0, stream>>>(w2, wt, 1024, 512);
    fc2_bf<<<dim3(512), dim3(512), 0, stream>>>(h, wt, b2, toki, ew, out);
  } else {
    u16* h = (u16*)(ws + 8 * MB + (256u << 10)); // old layout
    fc1_kernel<<<dim3(2048), dim3(256), 0, stream>>>(x, toki, w1, b1, h);
    fc2_kernel<<<dim3(1024), dim3(256), 0, stream>>>(h, w2, b2, toki, ew, out);
  }
}

// Round 15
// 408.369 us; speedup vs baseline: 1.0144x; 1.0144x over previous
//
#include <hip/hip_runtime.h>
#include <math.h>

#define N_TOK 32768
#define DIM   512
#define NEXP  64
#define HID   1024
#define CAP   512

typedef float  f32x4  __attribute__((ext_vector_type(4)));
typedef short  bf16x8 __attribute__((ext_vector_type(8)));
typedef unsigned short u16;

#define GET4(v, jj) ((jj) == 0 ? (v).x : (jj) == 1 ? (v).y : (jj) == 2 ? (v).z : (v).w)

__device__ __forceinline__ u16 f2bf(float f) {
  unsigned u = __float_as_uint(f);
  u += 0x7FFFu + ((u >> 16) & 1u);   // RNE
  return (u16)(u >> 16);
}
__device__ __forceinline__ unsigned enc_f(float f) {  // monotone f32 -> u32
  unsigned u = __float_as_uint(f);
  return (u & 0x80000000u) ? ~u : (u | 0x80000000u);
}
__device__ __forceinline__ float dec_f(unsigned k) {
  unsigned u = (k & 0x80000000u) ? (k & 0x7FFFFFFFu) : ~k;
  return __uint_as_float(u);
}
__device__ __forceinline__ void gl16(const u16* g, u16* l) {
  __builtin_amdgcn_global_load_lds(
      (const __attribute__((address_space(1))) unsigned int*)g,
      (__attribute__((address_space(3))) unsigned int*)l, 16, 0, 0);
}
// exact-enough erf (A&S 7.1.26, |eps|<=1.5e-7) -> gelu
__device__ __forceinline__ float gelu_f(float v) {
  float x = fabsf(v) * 0.70710678118654752f;
  float tt = 1.0f / (1.0f + 0.3275911f * x);
  float poly = tt * (0.254829592f + tt * (-0.284496736f + tt * (1.421413741f +
               tt * (-1.453152027f + tt * 1.061405429f))));
  float erfabs = 1.0f - poly * __expf(-x * x);
  float erfv = v >= 0.f ? erfabs : -erfabs;
  return 0.5f * v * (1.0f + erfv);
}

// ---------------- router: LDS-tiled fp32 SGEMM, 64 tok x 64 exp per block ----------------
// Also emits xb = bf16(x) as a by-product.
__global__ __launch_bounds__(256)
void router_kernel(const float* __restrict__ x, const float* __restrict__ rw,
                   float* __restrict__ logitsT, u16* __restrict__ xb) {
  __shared__ float As[32][68];   // [k][m]
  __shared__ float Bs[32][68];   // [k][e]
  const int t = threadIdx.x;
  const int n0 = blockIdx.x * 64;
  const int ty = t >> 4, tx = t & 15;
  const int am = t >> 2, akq = (t & 3) * 8;
  const int bk = t >> 3, beq = (t & 7) * 8;
  const float* xrow = x + (size_t)(n0 + am) * DIM + akq;
  u16* xbrow = xb ? (xb + (size_t)(n0 + am) * DIM + akq) : (u16*)0;
  const float* brow = rw + (size_t)bk * NEXP + beq;

  float acc[4][4] = {};
  for (int k0 = 0; k0 < DIM; k0 += 32) {
    float4 a0 = *(const float4*)(xrow + k0);
    float4 a1 = *(const float4*)(xrow + k0 + 4);
    float4 b0 = *(const float4*)(brow + (size_t)k0 * NEXP);
    float4 b1 = *(const float4*)(brow + (size_t)k0 * NEXP + 4);
    if (xbrow) {
      uint4 o;
      o.x = f2bf(a0.x) | ((unsigned)f2bf(a0.y) << 16);
      o.y = f2bf(a0.z) | ((unsigned)f2bf(a0.w) << 16);
      o.z = f2bf(a1.x) | ((unsigned)f2bf(a1.y) << 16);
      o.w = f2bf(a1.z) | ((unsigned)f2bf(a1.w) << 16);
      *(uint4*)(xbrow + k0) = o;
    }
    __syncthreads();
    As[akq + 0][am] = a0.x; As[akq + 1][am] = a0.y;
    As[akq + 2][am] = a0.z; As[akq + 3][am] = a0.w;
    As[akq + 4][am] = a1.x; As[akq + 5][am] = a1.y;
    As[akq + 6][am] = a1.z; As[akq + 7][am] = a1.w;
    *(float4*)&Bs[bk][beq] = b0;
    *(float4*)&Bs[bk][beq + 4] = b1;
    __syncthreads();
#pragma unroll
    for (int k = 0; k < 32; ++k) {
      float4 av = *(const float4*)&As[k][ty * 4];
      float4 bv = *(const float4*)&Bs[k][tx * 4];
#pragma unroll
      for (int i = 0; i < 4; ++i)
#pragma unroll
        for (int j = 0; j < 4; ++j)
          acc[i][j] += GET4(av, i) * GET4(bv, j);
    }
  }
#pragma unroll
  for (int j = 0; j < 4; ++j) {
    float4 o; o.x = acc[0][j]; o.y = acc[1][j]; o.z = acc[2][j]; o.w = acc[3][j];
    *(float4*)(logitsT + (size_t)(tx * 4 + j) * N_TOK + n0 + ty * 4) = o;
  }
}

// ------------- topk: ballot-aggregated histograms + parallel scans -------------
__global__ __launch_bounds__(1024)
void topk_kernel(const float* __restrict__ logitsT, int* __restrict__ tok_idx,
                 float* __restrict__ expw, float* __restrict__ auxout) {
  const int e = blockIdx.x;
  const int t = threadIdx.x;
  const int lane = t & 63;
  const float* row = logitsT + (size_t)e * N_TOK;

  unsigned key[32];          // token n = j*1024 + t
#pragma unroll
  for (int j = 0; j < 32; ++j) key[j] = enc_f(row[j * 1024 + t]);

  __shared__ unsigned ured[1024];
  __shared__ float    fred[1024];
  __shared__ unsigned hist[256];
  __shared__ unsigned sh_chosen, sh_rem, sh_x, sh_pos;

  // elect-and-count histogram add: one atomic per DISTINCT bucket per wave
#define HIST_ELECT(BKT, PRED) do { \
    const unsigned bkt_ = (BKT); \
    const bool pred_ = (PRED); \
    unsigned long long pend_ = __ballot(pred_ ? 1 : 0); \
    while (pend_) { \
      const int lead_ = (int)__builtin_ctzll(pend_); \
      const unsigned b0_ = __shfl(bkt_, lead_); \
      const unsigned long long match_ = __ballot((pred_ && bkt_ == b0_) ? 1 : 0); \
      if (lane == lead_) atomicAdd(&hist[b0_], (unsigned)__builtin_popcountll(match_)); \
      pend_ &= ~match_; \
    } } while (0)

  // ballot-compacted emission into tok_idx/expw
#define EMIT(PRED, NVAL, KVAL) do { \
    const bool em_ = (PRED); \
    const unsigned long long mask_ = __ballot(em_ ? 1 : 0); \
    if (mask_) { \
      const int lead_ = (int)__builtin_ctzll(mask_); \
      unsigned base_ = 0; \
      if (lane == lead_) base_ = atomicAdd(&sh_pos, (unsigned)__builtin_popcountll(mask_)); \
      base_ = __shfl(base_, lead_); \
      if (em_) { \
        const unsigned p_ = base_ + (unsigned)__builtin_popcountll(mask_ & ((1ULL << lane) - 1ULL)); \
        tok_idx[e * CAP + p_] = (NVAL); \
        expw[e * CAP + p_] = expf(dec_f(KVAL) - m) * invZ; \
      } \
    } } while (0)

  // block max (deterministic tree)
  unsigned km = 0;
#pragma unroll
  for (int j = 0; j < 32; ++j) km = key[j] > km ? key[j] : km;
  ured[t] = km;
  __syncthreads();
  for (int s = 512; s > 0; s >>= 1) {
    if (t < s) { unsigned o = ured[t + s]; if (o > ured[t]) ured[t] = o; }
    __syncthreads();
  }
  const float m = dec_f(ured[0]);

  float ssum = 0.f;
#pragma unroll
  for (int j = 0; j < 32; ++j) ssum += expf(dec_f(key[j]) - m);
  fred[t] = ssum;
  __syncthreads();
  for (int s = 512; s > 0; s >>= 1) {
    if (t < s) fred[t] += fred[t + s];
    __syncthreads();
  }
  const float invZ = 1.0f / fred[0];

  if (t == 0) { sh_rem = CAP; sh_pos = 0; }
  __syncthreads();

  unsigned live = 0xFFFFFFFFu;
  unsigned prefix = 0;
  for (int pass = 0; pass < 4; ++pass) {
    const int shift = 24 - pass * 8;
    const unsigned need = sh_rem;
    if (t < 256) hist[t] = 0;
    __syncthreads();
#pragma unroll
    for (int j = 0; j < 32; ++j)
      HIST_ELECT((key[j] >> shift) & 0xFFu, (live >> j) & 1u);
    __syncthreads();
    // suffix scan (descending cumulative): hist[t] := sum_{b>=t} hist[b]
    for (int off = 1; off < 256; off <<= 1) {
      unsigned v = 0;
      if (t < 256) { v = hist[t]; if (t + off < 256) v += hist[t + off]; }
      __syncthreads();
      if (t < 256) hist[t] = v;
      __syncthreads();
    }
    if (t < 256) {
      const unsigned s = hist[t];
      const unsigned snx = (t == 255) ? 0u : hist[t + 1];
      if (s >= need && snx < need) { sh_chosen = (unsigned)t; sh_rem = need - snx; }
    }
    __syncthreads();
    const unsigned ch = sh_chosen;
#pragma unroll
    for (int j = 0; j < 32; ++j)
      if (((key[j] >> shift) & 0xFFu) != ch) live &= ~(1u << j);
    prefix = (prefix << 8) | ch;
    __syncthreads();
  }
  const unsigned ustar = prefix;   // `live` marks keys == ustar

  // emit all strictly-greater keys (ballot-compacted)
#pragma unroll
  for (int j = 0; j < 32; ++j)
    EMIT(key[j] > ustar, j * 1024 + t, key[j]);
  __syncthreads();
  const unsigned padv = CAP - sh_pos;   // #ties to take (>=1), smallest index first

  // tie pass 1: bucket = n>>7, ascending prefix scan
  if (t < 256) hist[t] = 0;
  __syncthreads();
#pragma unroll
  for (int j = 0; j < 32; ++j)
    HIST_ELECT((unsigned)((j * 1024 + t) >> 7), (live >> j) & 1u);
  __syncthreads();
  for (int off = 1; off < 256; off <<= 1) {
    unsigned v = 0;
    if (t < 256) { v = hist[t]; if (t >= off) v += hist[t - off]; }
    __syncthreads();
    if (t < 256) hist[t] = v;
    __syncthreads();
  }
  if (t < 256) {
    const unsigned s = hist[t];
    const unsigned sp = (t == 0) ? 0u : hist[t - 1];
    if (s >= padv && sp < padv) { sh_chosen = (unsigned)t; sh_rem = padv - sp; }
  }
  __syncthreads();
  const unsigned hb = sh_chosen, rem = sh_rem;

  // tie pass 2: bucket = n&127 within chosen 128-block
  if (t < 256) hist[t] = 0;
  __syncthreads();
#pragma unroll
  for (int j = 0; j < 32; ++j) {
    const int n = j * 1024 + t;
    HIST_ELECT((unsigned)(n & 127),
               (((live >> j) & 1u) && ((unsigned)(n >> 7) == hb)));
  }
  __syncthreads();
  for (int off = 1; off < 256; off <<= 1) {
    unsigned v = 0;
    if (t < 256) { v = hist[t]; if (t >= off) v += hist[t - off]; }
    __syncthreads();
    if (t < 256) hist[t] = v;
    __syncthreads();
  }
  if (t < 256) {
    const unsigned s = hist[t];
    const unsigned sp = (t == 0) ? 0u : hist[t - 1];
    if (s >= rem && sp < rem) sh_x = (hb << 7) | (unsigned)t;
  }
  __syncthreads();
  const int X = (int)sh_x;              // padv-th smallest tie index

#pragma unroll
  for (int j = 0; j < 32; ++j) {
    const int n = j * 1024 + t;
    EMIT(((live >> j) & 1u) && n <= X, n, key[j]);
  }
  if (e == 0 && t == 0) { auxout[0] = 2.44140625e-4f; auxout[1] = 0.015625f; }
#undef HIST_ELECT
#undef EMIT
}

// ---------------- prep: per-expert transpose+cvt: f32 [E][R][C] -> bf16 [E][C][R] ----------------
__global__ __launch_bounds__(256)
void transpose_cvt_kernel(const float* __restrict__ in, u16* __restrict__ outp,
                          int R, int C) {
  __shared__ u16 tile[64][66];
  const int e = blockIdx.z;
  const int r0 = blockIdx.y * 64, c0 = blockIdx.x * 64;
  const int t = threadIdx.x;
  {
    const int r = t >> 2, cs = (t & 3) * 16;
    const float* ip = in + ((size_t)e * R + (r0 + r)) * C + c0 + cs;
#pragma unroll
    for (int q = 0; q < 4; ++q) {
      float4 v = *(const float4*)(ip + q * 4);
      tile[r][cs + q * 4 + 0] = f2bf(v.x);
      tile[r][cs + q * 4 + 1] = f2bf(v.y);
      tile[r][cs + q * 4 + 2] = f2bf(v.z);
      tile[r][cs + q * 4 + 3] = f2bf(v.w);
    }
  }
  __syncthreads();
  {
    const int c = t >> 2, rs = (t & 3) * 16;
    u16* op = outp + ((size_t)e * C + (c0 + c)) * R + r0 + rs;
    uint4 o0, o1;
    o0.x = tile[rs + 0][c]  | ((unsigned)tile[rs + 1][c]  << 16);
    o0.y = tile[rs + 2][c]  | ((unsigned)tile[rs + 3][c]  << 16);
    o0.z = tile[rs + 4][c]  | ((unsigned)tile[rs + 5][c]  << 16);
    o0.w = tile[rs + 6][c]  | ((unsigned)tile[rs + 7][c]  << 16);
    o1.x = tile[rs + 8][c]  | ((unsigned)tile[rs + 9][c]  << 16);
    o1.y = tile[rs + 10][c] | ((unsigned)tile[rs + 11][c] << 16);
    o1.z = tile[rs + 12][c] | ((unsigned)tile[rs + 13][c] << 16);
    o1.w = tile[rs + 14][c] | ((unsigned)tile[rs + 15][c] << 16);
    *(uint4*)(op) = o0;
    *(uint4*)(op + 8) = o1;
  }
}

// ===================== bf16 GEMMs: BM128 x BN256, BK=32, 3-buf depth-2, 72KB LDS (2 blocks/CU) =====================
#define A_EL 4096      // 128*32 elems (8 KB)
#define B_EL 8192      // 256*32 elems (16 KB)

#define LDSW(base, row, hi4v) \
  (*(const bf16x8*)((const char*)(base) + (row) * 64 + ((((hi4v) ^ (((row) >> 1) & 3))) << 4)))

#define STG3(bs, k0) do { \
  gl16(aSrc + (k0), AsmF + (bs) * A_EL + wOff); \
  gl16(bSrc0 + (k0), BsmF + (bs) * B_EL + wOff); \
  gl16(bSrc1 + (k0), BsmF + (bs) * B_EL + wOff + 4096); \
} while (0)

__global__ __launch_bounds__(512, 4)
void fc1_bf(const u16* __restrict__ xb, const int* __restrict__ tok_idx,
            const u16* __restrict__ w1t, const float* __restrict__ b1,
            u16* __restrict__ h) {
  const int p = blockIdx.x;
  const int l = (p & 7) * 128 + (p >> 3);        // bijective XCD remap (1024 = 8*128)
  const int e  = l >> 4;
  const int mt = (l >> 2) & 3;
  const int nt = l & 3;
  const int m0 = mt * 128, n0 = nt * 256;
  const int t = threadIdx.x;
  const int lane = t & 63, wave = t >> 6;        // 8 waves
  const int wm = wave >> 2, wn = wave & 3;       // 2m x 4n, per-wave C 64x64

  __shared__ __align__(16) u16 AsmF[3 * A_EL];   // 24 KB
  __shared__ __align__(16) u16 BsmF[3 * B_EL];   // 48 KB

  const int kc = ((lane & 3) ^ ((lane >> 3) & 3)) * 8;  // pre-swizzled k elem offset
  const int rloc = lane >> 2;                    // 0..15
  const int wOff = wave * 512;                   // 16 rows x 32 elems

  const int arow = wave * 16 + rloc;             // 0..127
  const int tok = tok_idx[e * CAP + m0 + arow];
  const u16* aSrc  = xb + (size_t)tok * DIM + kc;
  const u16* bSrc0 = w1t + ((size_t)e * HID + n0 + arow) * DIM + kc;
  const u16* bSrc1 = w1t + ((size_t)e * HID + n0 + 128 + arow) * DIM + kc;

  f32x4 acc[4][4] = {};
  const int lr = lane & 15, hi4 = lane >> 4;

  STG3(0, 0);     // K-tile 0 -> buf 0
  STG3(1, 32);    // K-tile 1 -> buf 1
  int cur = 0;
  const int KT = DIM / 32;                       // 16
  for (int tt = 0; tt < KT; ++tt) {
    if (tt < KT - 1) asm volatile("s_waitcnt vmcnt(3)" ::: "memory");
    else             asm volatile("s_waitcnt vmcnt(0)" ::: "memory");
    __builtin_amdgcn_s_barrier();
    const u16* Ab = AsmF + cur * A_EL;
    const u16* Bb = BsmF + cur * B_EL;
    bf16x8 af[4], bf[4];
#pragma unroll
    for (int mi = 0; mi < 4; ++mi) af[mi] = LDSW(Ab, wm * 64 + mi * 16 + lr, hi4);
#pragma unroll
    for (int ni = 0; ni < 4; ++ni) bf[ni] = LDSW(Bb, wn * 64 + ni * 16 + lr, hi4);
    if (tt + 2 < KT) {
      const int bs = (tt + 2) % 3;
      STG3(bs, (tt + 2) * 32);
    }
    __builtin_amdgcn_s_setprio(1);
#pragma unroll
    for (int mi = 0; mi < 4; ++mi)
#pragma unroll
      for (int ni = 0; ni < 4; ++ni)
        acc[mi][ni] = __builtin_amdgcn_mfma_f32_16x16x32_bf16(af[mi], bf[ni], acc[mi][ni], 0, 0, 0);
    __builtin_amdgcn_s_setprio(0);
    __builtin_amdgcn_s_barrier();
    cur = cur == 2 ? 0 : cur + 1;
  }

  const int lq = lane >> 4, lc = lane & 15;
#pragma unroll
  for (int nj = 0; nj < 4; ++nj) {
    const int n_l = wn * 64 + nj * 16 + lc;
    const float bias = b1[e * HID + n0 + n_l];
#pragma unroll
    for (int mi = 0; mi < 4; ++mi) {
#pragma unroll
      for (int j = 0; j < 4; ++j) {
        const int m_l = wm * 64 + mi * 16 + lq * 4 + j;
        float v = acc[mi][nj][j] + bias;
        h[((size_t)(e * CAP + m0 + m_l)) * HID + (n0 + n_l)] = f2bf(gelu_f(v));
      }
    }
  }
}

__global__ __launch_bounds__(512, 4)
void fc2_bf(const u16* __restrict__ h, const u16* __restrict__ w2t,
            const float* __restrict__ b2, const int* __restrict__ tok_idx,
            const float* __restrict__ expw, float* __restrict__ out) {
  const int p = blockIdx.x;
  const int l = (p & 7) * 64 + (p >> 3);         // bijective XCD remap (512 = 8*64)
  const int e  = l >> 3;
  const int mt = (l >> 1) & 3;
  const int nt = l & 1;
  const int m0 = mt * 128, n0 = nt * 256;
  const int t = threadIdx.x;
  const int lane = t & 63, wave = t >> 6;
  const int wm = wave >> 2, wn = wave & 3;

  __shared__ __align__(16) u16 AsmF[3 * A_EL];
  __shared__ __align__(16) u16 BsmF[3 * B_EL];

  const int kc = ((lane & 3) ^ ((lane >> 3) & 3)) * 8;
  const int rloc = lane >> 2;
  const int wOff = wave * 512;

  const int arow = wave * 16 + rloc;
  const u16* aSrc  = h + ((size_t)(e * CAP + m0 + arow)) * HID + kc;
  const u16* bSrc0 = w2t + ((size_t)e * DIM + n0 + arow) * HID + kc;
  const u16* bSrc1 = w2t + ((size_t)e * DIM + n0 + 128 + arow) * HID + kc;

  f32x4 acc[4][4] = {};
  const int lr = lane & 15, hi4 = lane >> 4;

  STG3(0, 0);
  STG3(1, 32);
  int cur = 0;
  const int KT = HID / 32;                       // 32
  for (int tt = 0; tt < KT; ++tt) {
    if (tt < KT - 1) asm volatile("s_waitcnt vmcnt(3)" ::: "memory");
    else             asm volatile("s_waitcnt vmcnt(0)" ::: "memory");
    __builtin_amdgcn_s_barrier();
    const u16* Ab = AsmF + cur * A_EL;
    const u16* Bb = BsmF + cur * B_EL;
    bf16x8 af[4], bf[4];
#pragma unroll
    for (int mi = 0; mi < 4; ++mi) af[mi] = LDSW(Ab, wm * 64 + mi * 16 + lr, hi4);
#pragma unroll
    for (int ni = 0; ni < 4; ++ni) bf[ni] = LDSW(Bb, wn * 64 + ni * 16 + lr, hi4);
    if (tt + 2 < KT) {
      const int bs = (tt + 2) % 3;
      STG3(bs, (tt + 2) * 32);
    }
    __builtin_amdgcn_s_setprio(1);
#pragma unroll
    for (int mi = 0; mi < 4; ++mi)
#pragma unroll
      for (int ni = 0; ni < 4; ++ni)
        acc[mi][ni] = __builtin_amdgcn_mfma_f32_16x16x32_bf16(af[mi], bf[ni], acc[mi][ni], 0, 0, 0);
    __builtin_amdgcn_s_setprio(0);
    __builtin_amdgcn_s_barrier();
    cur = cur == 2 ? 0 : cur + 1;
  }

  const int lq = lane >> 4, lc = lane & 15;
  int   tokm[4][4];
  float wgt[4][4];
#pragma unroll
  for (int mi = 0; mi < 4; ++mi)
#pragma unroll
    for (int j = 0; j < 4; ++j) {
      const int m_l = wm * 64 + mi * 16 + lq * 4 + j;
      tokm[mi][j] = tok_idx[e * CAP + m0 + m_l];
      wgt[mi][j]  = expw[e * CAP + m0 + m_l];
    }
#pragma unroll
  for (int nj = 0; nj < 4; ++nj) {
    const int n_l = wn * 64 + nj * 16 + lc;
    const float bias = b2[e * DIM + n0 + n_l];
#pragma unroll
    for (int mi = 0; mi < 4; ++mi)
#pragma unroll
      for (int j = 0; j < 4; ++j) {
        float v = (acc[mi][nj][j] + bias) * wgt[mi][j];
        atomicAdd(out + (size_t)tokm[mi][j] * DIM + (n0 + n_l), v);
      }
  }
}

// ===================== fallback f32-input GEMMs (ws too small) =====================
#define SWZ(row, cb) ((cb) ^ (((((row) >> 3) ^ (row)) & 7) << 4))

__global__ __launch_bounds__(256)
void fc1_kernel(const float* __restrict__ x, const int* __restrict__ tok_idx,
                const float* __restrict__ w1, const float* __restrict__ b1,
                u16* __restrict__ h) {
  const int bx = blockIdx.x;
  const int e  = bx >> 5;
  const int mt = (bx >> 3) & 3;
  const int nt = bx & 7;
  const int m0 = mt * 128, n0 = nt * 128;
  const int t = threadIdx.x;
  const int lane = t & 63, wave = t >> 6;
  const int wm = wave >> 1, wn = wave & 1;

  __shared__ __align__(16) u16 Asm[128 * 64];
  __shared__ __align__(16) u16 Bsm[128 * 64];

  const int arq = t & 31, akq = t >> 5;
  int tokr[4];
#pragma unroll
  for (int j = 0; j < 4; ++j) tokr[j] = tok_idx[e * CAP + m0 + arq * 4 + j];
  const int nq = t & 31, kq = t >> 5;
  const float* bptr = w1 + (size_t)e * DIM * HID + n0 + nq * 4;

  f32x4 acc[4][4] = {};

  for (int k0 = 0; k0 < DIM; k0 += 64) {
    float4 av0[4], av1[4];
#pragma unroll
    for (int j = 0; j < 4; ++j) {
      const float* ap = x + (size_t)tokr[j] * DIM + k0 + akq * 8;
      av0[j] = *(const float4*)(ap);
      av1[j] = *(const float4*)(ap + 4);
    }
    float4 bv[8];
#pragma unroll
    for (int kk = 0; kk < 8; ++kk)
      bv[kk] = *(const float4*)(bptr + (size_t)(k0 + kq * 8 + kk) * HID);
    __syncthreads();
#pragma unroll
    for (int j = 0; j < 4; ++j) {
      const int row = arq * 4 + j;
      ushort4 w0, w1v;
      w0.x = f2bf(av0[j].x); w0.y = f2bf(av0[j].y); w0.z = f2bf(av0[j].z); w0.w = f2bf(av0[j].w);
      w1v.x = f2bf(av1[j].x); w1v.y = f2bf(av1[j].y); w1v.z = f2bf(av1[j].z); w1v.w = f2bf(av1[j].w);
      *(ushort4*)((char*)Asm + row * 128 + SWZ(row, (akq * 8 + 0) * 2)) = w0;
      *(ushort4*)((char*)Asm + row * 128 + SWZ(row, (akq * 8 + 4) * 2)) = w1v;
    }
#pragma unroll
    for (int g = 0; g < 2; ++g) {
#pragma unroll
      for (int j = 0; j < 4; ++j) {
        ushort4 wv;
        wv.x = f2bf(GET4(bv[g * 4 + 0], j));
        wv.y = f2bf(GET4(bv[g * 4 + 1], j));
        wv.z = f2bf(GET4(bv[g * 4 + 2], j));
        wv.w = f2bf(GET4(bv[g * 4 + 3], j));
        const int row = nq * 4 + j;
        const int cb = (kq * 8 + g * 4) * 2;
        *(ushort4*)((char*)Bsm + row * 128 + SWZ(row, cb)) = wv;
      }
    }
    __syncthreads();
#pragma unroll
    for (int ks = 0; ks < 2; ++ks) {
      bf16x8 af[4], bf[4];
#pragma unroll
      for (int mi = 0; mi < 4; ++mi) {
        const int row = wm * 64 + mi * 16 + (lane & 15);
        const int cb = ks * 64 + (lane >> 4) * 16;
        af[mi] = *(const bf16x8*)((const char*)Asm + row * 128 + SWZ(row, cb));
      }
#pragma unroll
      for (int ni = 0; ni < 4; ++ni) {
        const int row = wn * 64 + ni * 16 + (lane & 15);
        const int cb = ks * 64 + (lane >> 4) * 16;
        bf[ni] = *(const bf16x8*)((const char*)Bsm + row * 128 + SWZ(row, cb));
      }
#pragma unroll
      for (int mi = 0; mi < 4; ++mi)
#pragma unroll
        for (int ni = 0; ni < 4; ++ni)
          acc[mi][ni] = __builtin_amdgcn_mfma_f32_16x16x32_bf16(af[mi], bf[ni], acc[mi][ni], 0, 0, 0);
    }
  }
  const int lq = lane >> 4, lc = lane & 15;
#pragma unroll
  for (int ni = 0; ni < 4; ++ni) {
    const int n_l = wn * 64 + ni * 16 + lc;
    const float bias = b1[e * HID + n0 + n_l];
#pragma unroll
    for (int mi = 0; mi < 4; ++mi) {
#pragma unroll
      for (int j = 0; j < 4; ++j) {
        const int m_l = wm * 64 + mi * 16 + lq * 4 + j;
        float v = acc[mi][ni][j] + bias;
        h[((size_t)(e * CAP + m0 + m_l)) * HID + (n0 + n_l)] = f2bf(gelu_f(v));
      }
    }
  }
}

__global__ __launch_bounds__(256)
void fc2_kernel(const u16* __restrict__ h, const float* __restrict__ w2,
                const float* __restrict__ b2, const int* __restrict__ tok_idx,
                const float* __restrict__ expw, float* __restrict__ out) {
  const int bx = blockIdx.x;
  const int e  = bx >> 4;
  const int mt = (bx >> 2) & 3;
  const int nt = bx & 3;
  const int m0 = mt * 128, n0 = nt * 128;
  const int t = threadIdx.x;
  const int lane = t & 63, wave = t >> 6;
  const int wm = wave >> 1, wn = wave & 1;

  __shared__ __align__(16) u16 Asm[128 * 64];
  __shared__ __align__(16) u16 Bsm[128 * 64];

  const int arq = t & 31, akq = t >> 5;
  const u16* aptr0 = h + ((size_t)(e * CAP + m0 + arq * 4)) * HID + akq * 8;
  const int nq = t & 31, kq = t >> 5;
  const float* bptr = w2 + (size_t)e * HID * DIM + n0 + nq * 4;

  f32x4 acc[4][4] = {};

  for (int k0 = 0; k0 < HID; k0 += 64) {
    uint4 av[4];
#pragma unroll
    for (int j = 0; j < 4; ++j)
      av[j] = *(const uint4*)(aptr0 + (size_t)j * HID + k0);
    float4 bv[8];
#pragma unroll
    for (int kk = 0; kk < 8; ++kk)
      bv[kk] = *(const float4*)(bptr + (size_t)(k0 + kq * 8 + kk) * DIM);
    __syncthreads();
#pragma unroll
    for (int j = 0; j < 4; ++j) {
      const int row = arq * 4 + j;
      *(uint4*)((char*)Asm + row * 128 + SWZ(row, akq * 16)) = av[j];
    }
#pragma unroll
    for (int g = 0; g < 2; ++g) {
#pragma unroll
      for (int j = 0; j < 4; ++j) {
        ushort4 wv;
        wv.x = f2bf(GET4(bv[g * 4 + 0], j));
        wv.y = f2bf(GET4(bv[g * 4 + 1], j));
        wv.z = f2bf(GET4(bv[g * 4 + 2], j));
        wv.w = f2bf(GET4(bv[g * 4 + 3], j));
        const int row = nq * 4 + j;
        const int cb = (kq * 8 + g * 4) * 2;
        *(ushort4*)((char*)Bsm + row * 128 + SWZ(row, cb)) = wv;
      }
    }
    __syncthreads();
#pragma unroll
    for (int ks = 0; ks < 2; ++ks) {
      bf16x8 af[4], bf[4];
#pragma unroll
      for (int mi = 0; mi < 4; ++mi) {
        const int row = wm * 64 + mi * 16 + (lane & 15);
        const int cb = ks * 64 + (lane >> 4) * 16;
        af[mi] = *(const bf16x8*)((const char*)Asm + row * 128 + SWZ(row, cb));
      }
#pragma unroll
      for (int ni = 0; ni < 4; ++ni) {
        const int row = wn * 64 + ni * 16 + (lane & 15);
        const int cb = ks * 64 + (lane >> 4) * 16;
        bf[ni] = *(const bf16x8*)((const char*)Bsm + row * 128 + SWZ(row, cb));
      }
#pragma unroll
      for (int mi = 0; mi < 4; ++mi)
#pragma unroll
        for (int ni = 0; ni < 4; ++ni)
          acc[mi][ni] = __builtin_amdgcn_mfma_f32_16x16x32_bf16(af[mi], bf[ni], acc[mi][ni], 0, 0, 0);
    }
  }
  const int lq = lane >> 4, lc = lane & 15;
  int   tokm[4][4];
  float wgt[4][4];
#pragma unroll
  for (int mi = 0; mi < 4; ++mi)
#pragma unroll
    for (int j = 0; j < 4; ++j) {
      const int m_l = wm * 64 + mi * 16 + lq * 4 + j;
      tokm[mi][j] = tok_idx[e * CAP + m0 + m_l];
      wgt[mi][j]  = expw[e * CAP + m0 + m_l];
    }
#pragma unroll
  for (int ni = 0; ni < 4; ++ni) {
    const int n_l = wn * 64 + ni * 16 + lc;
    const float bias = b2[e * DIM + n0 + n_l];
#pragma unroll
    for (int mi = 0; mi < 4; ++mi)
#pragma unroll
      for (int j = 0; j < 4; ++j) {
        float v = (acc[mi][ni][j] + bias) * wgt[mi][j];
        atomicAdd(out + (size_t)tokm[mi][j] * DIM + (n0 + n_l), v);
      }
  }
}

extern "C" void kernel_launch(void* const* d_in, const int* in_sizes, int n_in,
                              void* d_out, int out_size, void* d_ws, size_t ws_size,
                              hipStream_t stream) {
  const float* x  = (const float*)d_in[0];
  const float* rw = (const float*)d_in[1];
  const float* w1 = (const float*)d_in[2];
  const float* b1 = (const float*)d_in[3];
  const float* w2 = (const float*)d_in[4];
  const float* b2 = (const float*)d_in[5];
  float* out = (float*)d_out;

  char* ws = (char*)d_ws;
  const size_t MB = 1u << 20;
  float* logits = (float*)ws;                                   // [0, 8M)
  int*   toki   = (int*)(ws + 8 * MB);                          // 128 KB
  float* ew     = (float*)(ws + 8 * MB + (128u << 10));         // 128 KB

  const size_t off_xb = 8 * MB + (256u << 10);   // 8.25M
  const size_t off_wt = off_xb + 32 * MB;        // 40.25M
  const size_t off_h  = off_wt + 64 * MB;        // 104.25M
  const size_t need   = off_h + 64 * MB;         // 168.25M
  const bool big = (ws_size >= need);

  u16* xb = big ? (u16*)(ws + off_xb) : (u16*)0;

  (void)hipMemsetAsync(d_out, 0, (size_t)out_size * sizeof(float), stream);
  router_kernel<<<dim3(512), dim3(256), 0, stream>>>(x, rw, logits, xb);
  topk_kernel<<<dim3(64), dim3(1024), 0, stream>>>(logits, toki, ew, out + (size_t)N_TOK * DIM);

  if (big) {
    u16* wt  = (u16*)(ws + off_wt);
    u16* h   = (u16*)(ws + off_h);
    transpose_cvt_kernel<<<dim3(16, 8, 64), dim3(256), 0, stream>>>(w1, wt, 512, 1024);
    fc1_bf<<<dim3(1024), dim3(512), 0, stream>>>(xb, toki, wt, b1, h);
    transpose_cvt_kernel<<<dim3(8, 16, 64), dim3(256), 0, stream>>>(w2, wt, 1024, 512);
    fc2_bf<<<dim3(512), dim3(512), 0, stream>>>(h, wt, b2, toki, ew, out);
  } else {
    u16* h = (u16*)(ws + 8 * MB + (256u << 10)); // old layout
    fc1_kernel<<<dim3(2048), dim3(256), 0, stream>>>(x, toki, w1, b1, h);
    fc2_kernel<<<dim3(1024), dim3(256), 0, stream>>>(h, w2, b2, toki, ew, out);
  }
}